// Round 8
// baseline (272.026 us; speedup 1.0000x reference)
//
#include <hip/hip_runtime.h>

#define BATCH 2048
#define VOCAB 256
#define KDIM 16384
#define WPR (KDIM / 32)          // 512 bit-words per row
#define BM 64
#define S_SPLIT 32
#define KCHUNK (KDIM / S_SPLIT)  // 512
#define NT (KCHUNK / 64)         // 8 K-tiles (of 64) per block
#define CW (KCHUNK / 32)         // 16 bit-words per row per chunk
#define LN10 2.302585092994046f

typedef __attribute__((ext_vector_type(8))) short short8;
typedef __attribute__((ext_vector_type(4))) float f32x4;
typedef __attribute__((ext_vector_type(2))) unsigned short u16x2;

__device__ __forceinline__ unsigned short f2bf_rne(float f) {
  unsigned int u = __float_as_uint(f);
  u += 0x7fffu + ((u >> 16) & 1u);
  return (unsigned short)(u >> 16);
}

// packed u16 multiply (v_pk_mul_lo_u16); both products fit in 16 bits
__device__ __forceinline__ unsigned int pkmul(unsigned int a, unsigned int b) {
  union { unsigned int u; u16x2 h; } x, y, r;
  x.u = a; y.u = b;
  r.h = x.h * y.h;
  return r.u;
}

// ---------------- log_w precompute: logw = bf16(log(10*sigmoid(raw))) -------
__global__ __launch_bounds__(256) void k_logw(const float* __restrict__ raw,
                                              unsigned short* __restrict__ logw) {
  int i = blockIdx.x * 256 + threadIdx.x;
  float4 x = ((const float4*)raw)[i];
  ushort4 r;
  r.x = f2bf_rne(LN10 - log1pf(expf(-x.x)));
  r.y = f2bf_rne(LN10 - log1pf(expf(-x.y)));
  r.z = f2bf_rne(LN10 - log1pf(expf(-x.z)));
  r.w = f2bf_rne(LN10 - log1pf(expf(-x.w)));
  ((ushort4*)logw)[i] = r;
}

// ---------------- bit-pack: binary fp32 {0,1} -> 1 bit; per-wave popcounts --
// 1 block per row; perfectly sequential coalesced float4 reads (HBM floor).
// Word w bit j = binary[r][w*32+j]. Wave wv writes partial count nact4[r*4+wv].
__global__ __launch_bounds__(256) void k_pack(const float* __restrict__ binary,
                                              unsigned int* __restrict__ bits,
                                              float* __restrict__ nact4) {
  const int r = blockIdx.x;
  const int t = threadIdx.x;
  const int lane = t & 63;
  const float4* src = (const float4*)(binary + (size_t)r * KDIM);
  unsigned int* wrow = bits + (size_t)r * WPR;
  float cnt = 0.f;
#pragma unroll
  for (int i = 0; i < 16; ++i) {
    float4 f = src[i * 256 + t];
    // values are exactly 0.0f or 1.0f; bit 29 of 0x3F800000 is 1
    unsigned int nib = ((__float_as_uint(f.x) >> 29) & 1u) |
                       ((__float_as_uint(f.y) >> 28) & 2u) |
                       ((__float_as_uint(f.z) >> 27) & 4u) |
                       ((__float_as_uint(f.w) >> 26) & 8u);
    unsigned int v = nib, p;
    p = __shfl_xor(v, 1, 64); v = (lane & 1) ? (p | (v << 4)) : (v | (p << 4));
    p = __shfl_xor(v, 2, 64); v = (lane & 2) ? (p | (v << 8)) : (v | (p << 8));
    p = __shfl_xor(v, 4, 64); v = (lane & 4) ? (p | (v << 16)) : (v | (p << 16));
    if ((t & 7) == 0) wrow[i * 32 + (t >> 3)] = v;
    cnt += (float)__popc(v); // 8 lanes of a group count the same word
  }
  cnt *= 0.125f;
  cnt += __shfl_xor(cnt, 1, 64);
  cnt += __shfl_xor(cnt, 2, 64);
  cnt += __shfl_xor(cnt, 4, 64);
  cnt += __shfl_xor(cnt, 8, 64);
  cnt += __shfl_xor(cnt, 16, 64);
  cnt += __shfl_xor(cnt, 32, 64);
  if (lane == 0) nact4[r * 4 + (t >> 6)] = cnt; // unique writer, no memset
}

// ---------------- main MFMA GEMM: barrier-free, zero LDS --------------------
// grid (32 splits, 32 m-blocks) = 1024 blocks; 256 thr (4 waves);
// __launch_bounds__(256,3) -> 12 waves/CU. XCD = sx%8 -> per-XCD working set
// = logw slice 1 MB + bits slice 1 MB (L2-resident; B has ZERO intra-block
// reuse, so LDS staging buys nothing - read straight to registers).
// K-loop fully unrolled: every global load uses a static 13-bit imm offset,
// no barriers, no shared resources -> waves drift, compiler pipelines loads.
// A expansion (r7): rep = byte*0x01010101; pk_mul by (0x3F80>>bit) -> bf16 1.0.
template <int PART>
__global__ __launch_bounds__(256, 3) void k_gemm(
    const unsigned int* __restrict__ bits, const unsigned short* __restrict__ logw,
    float* __restrict__ outp) {
  const int tid = threadIdx.x;
  const int wv = tid >> 6;
  const int lane = tid & 63;
  const int l15 = lane & 15;
  const int lhi = lane >> 4;
  const int sh8 = lhi * 8;
  const int sx = blockIdx.x;        // k-split
  const int m0 = blockIdx.y * BM;

  // B bases: wave-exclusive vocab rows wv*64 + n*16 + l15
  const unsigned short* bb0 = logw + (size_t)(wv * 64 + l15) * KDIM + sx * KCHUNK + lhi * 8;
  const unsigned short* bb1 = bb0 + (size_t)16 * KDIM;
  const unsigned short* bb2 = bb0 + (size_t)32 * KDIM;
  const unsigned short* bb3 = bb0 + (size_t)48 * KDIM;
  // A bit-word bases: batch rows m0 + m*16 + l15 (lhi broadcasts)
  const unsigned int* wp0 = bits + (size_t)(m0 + l15) * WPR + sx * CW;
  const unsigned int* wp1 = wp0 + 16 * WPR;
  const unsigned int* wp2 = wp0 + 32 * WPR;
  const unsigned int* wp3 = wp0 + 48 * WPR;

  f32x4 acc[4][4];
#pragma unroll
  for (int m = 0; m < 4; ++m)
#pragma unroll
    for (int n = 0; n < 4; ++n) acc[m][n] = f32x4{0.f, 0.f, 0.f, 0.f};

#pragma unroll
  for (int j = 0; j < NT / 2; ++j) {      // j: pair of K-tiles (words 4j..4j+3)
    uint4 w0 = *(const uint4*)(wp0 + 4 * j);
    uint4 w1 = *(const uint4*)(wp1 + 4 * j);
    uint4 w2 = *(const uint4*)(wp2 + 4 * j);
    uint4 w3 = *(const uint4*)(wp3 + 4 * j);
#pragma unroll
    for (int h = 0; h < 2; ++h) {         // tile t = 2j+h, k-window t*64
      const int off = (2 * j + h) * 64;   // compile-time
      short8 bf[4][2];
#pragma unroll
      for (int ks = 0; ks < 2; ++ks) {
        bf[0][ks] = *(const short8*)(bb0 + off + ks * 32);
        bf[1][ks] = *(const short8*)(bb1 + off + ks * 32);
        bf[2][ks] = *(const short8*)(bb2 + off + ks * 32);
        bf[3][ks] = *(const short8*)(bb3 + off + ks * 32);
      }
#pragma unroll
      for (int ks = 0; ks < 2; ++ks) {
#pragma unroll
        for (int m = 0; m < 4; ++m) {
          const uint4 wm = (m == 0) ? w0 : (m == 1) ? w1 : (m == 2) ? w2 : w3;
          const unsigned int word =
              h ? (ks ? wm.w : wm.z) : (ks ? wm.y : wm.x);
          const unsigned int rep = ((word >> sh8) & 0xffu) * 0x01010101u;
          union { unsigned int u[4]; short8 s; } ex;
          ex.u[0] = pkmul(rep & 0x00020001u, 0x1FC03F80u);
          ex.u[1] = pkmul(rep & 0x00080004u, 0x07F00FE0u);
          ex.u[2] = pkmul(rep & 0x00200010u, 0x01FC03F8u);
          ex.u[3] = pkmul(rep & 0x00800040u, 0x007F00FEu);
#pragma unroll
          for (int n = 0; n < 4; ++n)
            acc[m][n] = __builtin_amdgcn_mfma_f32_16x16x32_bf16(
                bf[n][ks], ex.s, acc[m][n], 0, 0, 0);
        }
      }
    }
  }

  // D layout (swapped operands): batch col = m*16+l15,
  // vocab row = wv*64 + n*16 + lhi*4 + i
  if (PART) {
#pragma unroll
    for (int m = 0; m < 4; ++m) {
      float* dst = outp + ((size_t)sx * BATCH + m0 + m * 16 + l15) * VOCAB +
                   wv * 64 + lhi * 4;
#pragma unroll
      for (int n = 0; n < 4; ++n)
        *(float4*)(dst + n * 16) =
            (float4){acc[m][n][0], acc[m][n][1], acc[m][n][2], acc[m][n][3]};
    }
  } else {
#pragma unroll
    for (int m = 0; m < 4; ++m)
#pragma unroll
      for (int n = 0; n < 4; ++n)
#pragma unroll
        for (int i = 0; i < 4; ++i)
          atomicAdd(&outp[(size_t)(m0 + m * 16 + l15) * VOCAB + wv * 64 +
                          n * 16 + lhi * 4 + i],
                    acc[m][n][i]);
  }
}

// ---------------- reduce: sum split partials, divide by n_active, exp -------
__global__ __launch_bounds__(256) void k_reduce(const float* __restrict__ part,
                                                const float* __restrict__ nact4,
                                                float* __restrict__ out) {
  int b = blockIdx.x;
  int v = threadIdx.x;
  float sum = 0.f;
#pragma unroll
  for (int i = 0; i < S_SPLIT; ++i)
    sum += part[((size_t)i * BATCH + b) * VOCAB + v];
  float n = nact4[b * 4] + nact4[b * 4 + 1] + nact4[b * 4 + 2] + nact4[b * 4 + 3];
  out[(size_t)b * VOCAB + v] = expf(sum / fmaxf(n, 1.f));
}

// ---------------- epilogue (atomic fallback path) ---------------------------
__global__ __launch_bounds__(256) void k_out(float* __restrict__ io,
                                             const float* __restrict__ nact4) {
  int b = blockIdx.x;
  int v = threadIdx.x;
  float n = nact4[b * 4] + nact4[b * 4 + 1] + nact4[b * 4 + 2] + nact4[b * 4 + 3];
  n = fmaxf(n, 1.0f);
  size_t idx = (size_t)b * VOCAB + v;
  io[idx] = expf(io[idx] / n);
}

extern "C" void kernel_launch(void* const* d_in, const int* in_sizes, int n_in,
                              void* d_out, int out_size, void* d_ws, size_t ws_size,
                              hipStream_t stream) {
  const float* binary = (const float*)d_in[0];
  const float* raw = (const float*)d_in[1];
  float* out = (float*)d_out;
  char* ws = (char*)d_ws;

  const size_t LOGW_B = (size_t)VOCAB * KDIM * 2;            // 8 MB
  const size_t BITS_B = (size_t)BATCH * WPR * 4;             // 4 MB
  const size_t NACT_B = (size_t)BATCH * 4 * 4;               // 32 KB
  const size_t PART_B = (size_t)S_SPLIT * BATCH * VOCAB * 4; // 64 MB
  unsigned short* logw = (unsigned short*)ws;
  unsigned int* bits = (unsigned int*)(ws + LOGW_B);
  float* nact4 = (float*)(ws + LOGW_B + BITS_B);
  float* part = (float*)(ws + LOGW_B + BITS_B + NACT_B);

  k_logw<<<(VOCAB * KDIM / 4) / 256, 256, 0, stream>>>(raw, logw);
  k_pack<<<BATCH, 256, 0, stream>>>(binary, bits, nact4);

  dim3 g(S_SPLIT, BATCH / BM);
  if (ws_size >= LOGW_B + BITS_B + NACT_B + PART_B) {
    k_gemm<1><<<g, 256, 0, stream>>>(bits, logw, part);
    k_reduce<<<BATCH, VOCAB, 0, stream>>>(part, nact4, out);
  } else {
    hipMemsetAsync(out, 0, (size_t)BATCH * VOCAB * sizeof(float), stream);
    k_gemm<0><<<g, 256, 0, stream>>>(bits, logw, out);
    k_out<<<BATCH, VOCAB, 0, stream>>>(out, nact4);
  }
}